// Round 3
// baseline (694.567 us; speedup 1.0000x reference)
//
#include <hip/hip_runtime.h>
#include <hip/hip_bf16.h>
#include <math.h>

// Problem constants
#define D_MODEL 256
#define DEPTH 2
#define D_INNER 512
#define D_STATE 16
#define D_CONV 4
#define DT_RANK 16
#define BATCH 2
#define SEQLEN 2048
#define MROWS (BATCH * SEQLEN)   // 4096

__device__ __forceinline__ float silu(float v) {
    return v / (1.0f + __expf(-v));
}

// ---------------------------------------------------------------------------
// LayerNorm: one block (256 threads) per row of 256 elements.
// ---------------------------------------------------------------------------
__global__ __launch_bounds__(256) void ln_kernel(
    const float* __restrict__ x, const float* __restrict__ w,
    const float* __restrict__ b, float* __restrict__ h)
{
    int row = blockIdx.x;
    int t = threadIdx.x;
    float v = x[(size_t)row * D_MODEL + t];
    float s = v, sq = v * v;
    #pragma unroll
    for (int off = 32; off > 0; off >>= 1) {
        s  += __shfl_xor(s, off);
        sq += __shfl_xor(sq, off);
    }
    __shared__ float ss[4], ssq[4];
    int wv = t >> 6;
    if ((t & 63) == 0) { ss[wv] = s; ssq[wv] = sq; }
    __syncthreads();
    s  = ss[0] + ss[1] + ss[2] + ss[3];
    sq = ssq[0] + ssq[1] + ssq[2] + ssq[3];
    float mu  = s * (1.0f / D_MODEL);
    float var = sq * (1.0f / D_MODEL) - mu * mu;
    float r = rsqrtf(var + 1e-5f);
    h[(size_t)row * D_MODEL + t] = (v - mu) * r * w[t] + b[t];
}

// ---------------------------------------------------------------------------
// in_proj: CT[e][m] = sum_k A[m][k] * W[e][k]   (C stored TRANSPOSED, e-major)
// A: MxK row-major, W: NxK row-major.  64x64x16 tile, 4x4 microtile.
// ---------------------------------------------------------------------------
__global__ __launch_bounds__(256) void gemm_nt_tstore(
    const float* __restrict__ A, const float* __restrict__ W,
    float* __restrict__ CT, int M, int N, int K)
{
    const int BM = 64, BN = 64, BK = 16;
    __shared__ float As[BK][BM + 4];
    __shared__ float Ws[BK][BN + 4];
    int bm = blockIdx.y * BM;
    int bn = blockIdx.x * BN;
    int t  = threadIdx.x;
    int tm = (t >> 4) << 2;
    int tn = (t & 15) << 2;
    int lr = t >> 2;
    int lk = (t & 3) << 2;
    const float* Ap = A + (size_t)(bm + lr) * K + lk;
    const float* Wp = W + (size_t)(bn + lr) * K + lk;
    float acc[4][4] = {};
    for (int k0 = 0; k0 < K; k0 += BK) {
        float4 av = *(const float4*)(Ap + k0);
        float4 wv = *(const float4*)(Wp + k0);
        __syncthreads();
        As[lk + 0][lr] = av.x; As[lk + 1][lr] = av.y;
        As[lk + 2][lr] = av.z; As[lk + 3][lr] = av.w;
        Ws[lk + 0][lr] = wv.x; Ws[lk + 1][lr] = wv.y;
        Ws[lk + 2][lr] = wv.z; Ws[lk + 3][lr] = wv.w;
        __syncthreads();
        #pragma unroll
        for (int k = 0; k < BK; k++) {
            float4 a4 = *(const float4*)&As[k][tm];
            float4 w4 = *(const float4*)&Ws[k][tn];
            float ar[4] = {a4.x, a4.y, a4.z, a4.w};
            float wr[4] = {w4.x, w4.y, w4.z, w4.w};
            #pragma unroll
            for (int i = 0; i < 4; i++)
                #pragma unroll
                for (int j = 0; j < 4; j++)
                    acc[i][j] = fmaf(ar[i], wr[j], acc[i][j]);
        }
    }
    // transposed store: CT[e][m], e = bn+tn+j, m = bm+tm..+3
    #pragma unroll
    for (int j = 0; j < 4; j++) {
        float4 o = { acc[0][j], acc[1][j], acc[2][j], acc[3][j] };
        *(float4*)(CT + (size_t)(bn + tn + j) * M + bm + tm) = o;
    }
}

// ---------------------------------------------------------------------------
// out_proj: C[m][e] = sum_k AT[k][m] * W[e][k] + resid[m][e]
// AT: KxM (k-major, i.e. A transposed), W: NxK row-major.
// ---------------------------------------------------------------------------
__global__ __launch_bounds__(256) void gemm_tn(
    const float* __restrict__ AT, const float* __restrict__ W,
    const float* __restrict__ resid, float* __restrict__ C,
    int M, int N, int K)
{
    const int BM = 64, BN = 64, BK = 16;
    __shared__ float As[BK][BM + 4];
    __shared__ float Ws[BK][BN + 4];
    int bm = blockIdx.y * BM;
    int bn = blockIdx.x * BN;
    int t  = threadIdx.x;
    int tm = (t >> 4) << 2;
    int tn = (t & 15) << 2;
    // A staging: 16 k-rows x 64 m, float4 along m (coalesced in AT)
    int alk = t >> 4;              // 0..15 k
    int alm = (t & 15) << 2;       // 0..60 m
    // W staging: NT-style
    int lr = t >> 2;
    int lk = (t & 3) << 2;
    const float* Wp = W + (size_t)(bn + lr) * K + lk;
    float acc[4][4] = {};
    for (int k0 = 0; k0 < K; k0 += BK) {
        float4 av = *(const float4*)(AT + (size_t)(k0 + alk) * M + bm + alm);
        float4 wv = *(const float4*)(Wp + k0);
        __syncthreads();
        *(float4*)&As[alk][alm] = av;
        Ws[lk + 0][lr] = wv.x; Ws[lk + 1][lr] = wv.y;
        Ws[lk + 2][lr] = wv.z; Ws[lk + 3][lr] = wv.w;
        __syncthreads();
        #pragma unroll
        for (int k = 0; k < BK; k++) {
            float4 a4 = *(const float4*)&As[k][tm];
            float4 w4 = *(const float4*)&Ws[k][tn];
            float ar[4] = {a4.x, a4.y, a4.z, a4.w};
            float wr[4] = {w4.x, w4.y, w4.z, w4.w};
            #pragma unroll
            for (int i = 0; i < 4; i++)
                #pragma unroll
                for (int j = 0; j < 4; j++)
                    acc[i][j] = fmaf(ar[i], wr[j], acc[i][j]);
        }
    }
    #pragma unroll
    for (int i = 0; i < 4; i++) {
        size_t off = (size_t)(bm + tm + i) * N + bn + tn;
        float4 r = *(const float4*)(resid + off);
        float4 o = { r.x + acc[i][0], r.y + acc[i][1],
                     r.z + acc[i][2], r.w + acc[i][3] };
        *(float4*)(C + off) = o;
    }
}

// ---------------------------------------------------------------------------
// Causal depthwise conv(4) + bias + SiLU on xi, and SiLU(z), all d-major.
// xzT: [1024][MROWS] (e-major). Block = (d, row-tile of 256).
// ---------------------------------------------------------------------------
__global__ __launch_bounds__(256) void convz_kernel(
    const float* __restrict__ xzT, const float* __restrict__ cw,
    const float* __restrict__ cb, float* __restrict__ xcT,
    float* __restrict__ zsT)
{
    int d = blockIdx.x;
    int row = blockIdx.y * 256 + threadIdx.x;
    int l = row & (SEQLEN - 1);
    const float* xi = xzT + (size_t)d * MROWS;
    float w0 = cw[d * D_CONV + 0], w1 = cw[d * D_CONV + 1];
    float w2 = cw[d * D_CONV + 2], w3 = cw[d * D_CONV + 3];
    float s = cb[d];
    if (l >= 3) s = fmaf(w0, xi[row - 3], s);
    if (l >= 2) s = fmaf(w1, xi[row - 2], s);
    if (l >= 1) s = fmaf(w2, xi[row - 1], s);
    s = fmaf(w3, xi[row], s);
    xcT[(size_t)d * MROWS + row] = silu(s);
    float z = xzT[(size_t)(D_INNER + d) * MROWS + row];
    zsT[(size_t)d * MROWS + row] = silu(z);
}

// ---------------------------------------------------------------------------
// dbl[row][e] = sum_k xcT[k][row] * xpw[e][k].  One wave per row, lanes 0..47.
// xcT loads are wave-uniform (broadcast); xpw is small and L2-resident.
// ---------------------------------------------------------------------------
__global__ __launch_bounds__(256) void xproj_kernel(
    const float* __restrict__ xcT, const float* __restrict__ xpw,
    float* __restrict__ dbl)
{
    int wv = threadIdx.x >> 6;
    int lane = threadIdx.x & 63;
    int row = blockIdx.x * 4 + wv;
    if (lane < 48) {
        const float* wr = xpw + (size_t)lane * D_INNER;
        float s = 0.f;
        for (int k = 0; k < D_INNER; k += 4) {
            float4 w4 = *(const float4*)(wr + k);
            float x0 = xcT[(size_t)(k + 0) * MROWS + row];
            float x1 = xcT[(size_t)(k + 1) * MROWS + row];
            float x2 = xcT[(size_t)(k + 2) * MROWS + row];
            float x3 = xcT[(size_t)(k + 3) * MROWS + row];
            s = fmaf(x0, w4.x, s); s = fmaf(x1, w4.y, s);
            s = fmaf(x2, w4.z, s); s = fmaf(x3, w4.w, s);
        }
        dbl[(size_t)row * 48 + lane] = s;
    }
}

// ---------------------------------------------------------------------------
// delta (transposed out): delT[d][row] = softplus(dt[row]·dpw[d] + dpb[d]).
// Thread = row; loop over 128 d per block.  dpw reads are wave-uniform.
// ---------------------------------------------------------------------------
__global__ __launch_bounds__(256) void delta_kernel(
    const float* __restrict__ dbl, const float* __restrict__ dpw,
    const float* __restrict__ dpb, float* __restrict__ delT)
{
    int row = blockIdx.x * 256 + threadIdx.x;
    int d0 = blockIdx.y * 128;
    float dts[DT_RANK];
    #pragma unroll
    for (int r = 0; r < DT_RANK; r++) dts[r] = dbl[(size_t)row * 48 + r];
    for (int dd = 0; dd < 128; dd++) {
        int d = d0 + dd;
        const float* wr = dpw + (size_t)d * DT_RANK;
        float s = dpb[d];
        #pragma unroll
        for (int r = 0; r < DT_RANK; r++) s = fmaf(dts[r], wr[r], s);
        float sp = (s > 20.f) ? s : log1pf(__expf(s));
        delT[(size_t)d * MROWS + row] = sp;
    }
}

// ---------------------------------------------------------------------------
// bcT[e][row] = dbl[row][16+e], e = 0..31 (B then C states).
// ---------------------------------------------------------------------------
__global__ __launch_bounds__(256) void bct_kernel(
    const float* __restrict__ dbl, float* __restrict__ bcT)
{
    int row = blockIdx.x * 256 + threadIdx.x;
    #pragma unroll
    for (int e = 0; e < 32; e++)
        bcT[(size_t)e * MROWS + row] = dbl[(size_t)row * 48 + DT_RANK + e];
}

// ---------------------------------------------------------------------------
// Selective scan, chunked parallel, all streams contiguous in l (d-major).
// One block per (b, d). 256 threads = 16 chunks x 16 states.
// ---------------------------------------------------------------------------
#define LC (SEQLEN / 16)   // 128 rows per chunk

__global__ __launch_bounds__(256) void scan_kernel(
    const float* __restrict__ delT, const float* __restrict__ xcT,
    const float* __restrict__ bcT, const float* __restrict__ zsT,
    const float* __restrict__ A_log, const float* __restrict__ Dp,
    float* __restrict__ yyT)
{
    int b = blockIdx.x >> 9;           // D_INNER == 512
    int d = blockIdx.x & 511;
    int t = threadIdx.x;
    int c = t >> 4, n = t & 15;        // chunk, state
    float a = -__expf(A_log[(size_t)d * D_STATE + n]);
    size_t base = (size_t)b * SEQLEN + (size_t)c * LC;   // row index (0..4095)

    const float* dlp = delT + (size_t)d * MROWS + base;
    const float* xvp = xcT  + (size_t)d * MROWS + base;
    const float* bnp = bcT  + (size_t)n * MROWS + base;
    const float* cnp = bcT  + (size_t)(D_STATE + n) * MROWS + base;
    const float* zsp = zsT  + (size_t)d * MROWS + base;
    float* yyp = yyT + (size_t)d * MROWS + base;

    __shared__ float Sarr[16][16];
    __shared__ float Parr[16][16];
    __shared__ float Hini[16][16];

    // Phase 1: chunk-local scan from h=0; accumulate sum(delta) for P.
    float h = 0.f, sd = 0.f;
    for (int j = 0; j < LC; j += 4) {
        float4 dl = *(const float4*)(dlp + j);
        float4 bn = *(const float4*)(bnp + j);
        float4 xv = *(const float4*)(xvp + j);
        sd += dl.x; h = fmaf(__expf(dl.x * a), h, dl.x * bn.x * xv.x);
        sd += dl.y; h = fmaf(__expf(dl.y * a), h, dl.y * bn.y * xv.y);
        sd += dl.z; h = fmaf(__expf(dl.z * a), h, dl.z * bn.z * xv.z);
        sd += dl.w; h = fmaf(__expf(dl.w * a), h, dl.w * bn.w * xv.w);
    }
    Sarr[c][n] = h;
    Parr[c][n] = __expf(a * sd);
    __syncthreads();

    // Phase 2: exclusive scan over the 16 chunk summaries (per state n).
    if (t < 16) {
        float hi = 0.f;
        #pragma unroll
        for (int cc = 0; cc < 16; cc++) {
            Hini[cc][t] = hi;
            hi = fmaf(Parr[cc][t], hi, Sarr[cc][t]);
        }
    }
    __syncthreads();

    // Phase 3: rescan from true initial state, produce gated output.
    h = Hini[c][n];
    float Dd = Dp[d];
    for (int j = 0; j < LC; j += 4) {
        float4 dl = *(const float4*)(dlp + j);
        float4 bn = *(const float4*)(bnp + j);
        float4 cn = *(const float4*)(cnp + j);
        float4 xv = *(const float4*)(xvp + j);
        float res[4];
        float dls[4] = {dl.x, dl.y, dl.z, dl.w};
        float bns[4] = {bn.x, bn.y, bn.z, bn.w};
        float cns[4] = {cn.x, cn.y, cn.z, cn.w};
        float xvs[4] = {xv.x, xv.y, xv.z, xv.w};
        #pragma unroll
        for (int jj = 0; jj < 4; jj++) {
            h = fmaf(__expf(dls[jj] * a), h, dls[jj] * bns[jj] * xvs[jj]);
            float p = h * cns[jj];
            p += __shfl_xor(p, 8, 16);
            p += __shfl_xor(p, 4, 16);
            p += __shfl_xor(p, 2, 16);
            p += __shfl_xor(p, 1, 16);
            res[jj] = p;
        }
        if (n == 0) {
            float4 zs = *(const float4*)(zsp + j);
            float4 o;
            o.x = (res[0] + xvs[0] * Dd) * zs.x;
            o.y = (res[1] + xvs[1] * Dd) * zs.y;
            o.z = (res[2] + xvs[2] * Dd) * zs.z;
            o.w = (res[3] + xvs[3] * Dd) * zs.w;
            *(float4*)(yyp + j) = o;
        }
    }
}

// ---------------------------------------------------------------------------
// Launch
// ---------------------------------------------------------------------------
extern "C" void kernel_launch(void* const* d_in, const int* in_sizes, int n_in,
                              void* d_out, int out_size, void* d_ws, size_t ws_size,
                              hipStream_t stream)
{
    const float* x    = (const float*)d_in[0];
    const float* lnw  = (const float*)d_in[1];
    const float* lnb  = (const float*)d_in[2];
    const float* ipw  = (const float*)d_in[3];
    const float* cw   = (const float*)d_in[4];
    const float* cb   = (const float*)d_in[5];
    const float* xpw  = (const float*)d_in[6];
    const float* dpw  = (const float*)d_in[7];
    const float* dpb  = (const float*)d_in[8];
    const float* alog = (const float*)d_in[9];
    const float* dpar = (const float*)d_in[10];
    const float* opw  = (const float*)d_in[11];
    float* out = (float*)d_out;

    float* ws = (float*)d_ws;
    float* hbuf = ws;                                       // 4096*256
    float* xzT  = hbuf + (size_t)MROWS * D_MODEL;           // 1024*4096
    float* xcT  = xzT  + (size_t)2 * D_INNER * MROWS;       // 512*4096
    float* zsT  = xcT  + (size_t)D_INNER * MROWS;           // 512*4096
    float* dblb = zsT  + (size_t)D_INNER * MROWS;           // 4096*48
    float* delT = dblb + (size_t)MROWS * 48;                // 512*4096
    float* bcT  = delT + (size_t)D_INNER * MROWS;           // 32*4096
    float* yyT  = bcT  + (size_t)32 * MROWS;                // 512*4096
    float* xbuf = yyT  + (size_t)D_INNER * MROWS;           // 4096*256

    for (int lyr = 0; lyr < DEPTH; lyr++) {
        const float* xin = (lyr == 0) ? x : xbuf;
        float* xout = (lyr == DEPTH - 1) ? out : xbuf;

        ln_kernel<<<MROWS, 256, 0, stream>>>(
            xin, lnw + lyr * D_MODEL, lnb + lyr * D_MODEL, hbuf);

        gemm_nt_tstore<<<dim3((2 * D_INNER) / 64, MROWS / 64), 256, 0, stream>>>(
            hbuf, ipw + (size_t)lyr * 2 * D_INNER * D_MODEL, xzT,
            MROWS, 2 * D_INNER, D_MODEL);

        convz_kernel<<<dim3(D_INNER, MROWS / 256), 256, 0, stream>>>(
            xzT, cw + (size_t)lyr * D_INNER * D_CONV, cb + lyr * D_INNER,
            xcT, zsT);

        xproj_kernel<<<MROWS / 4, 256, 0, stream>>>(
            xcT, xpw + (size_t)lyr * 48 * D_INNER, dblb);

        delta_kernel<<<dim3(MROWS / 256, 4), 256, 0, stream>>>(
            dblb, dpw + (size_t)lyr * D_INNER * DT_RANK, dpb + lyr * D_INNER,
            delT);

        bct_kernel<<<MROWS / 256, 256, 0, stream>>>(dblb, bcT);

        scan_kernel<<<BATCH * D_INNER, 256, 0, stream>>>(
            delT, xcT, bcT, zsT,
            alog + (size_t)lyr * D_INNER * D_STATE, dpar + lyr * D_INNER, yyT);

        gemm_tn<<<dim3(D_MODEL / 64, MROWS / 64), 256, 0, stream>>>(
            yyT, opw + (size_t)lyr * D_MODEL * D_INNER, xin, xout,
            MROWS, D_MODEL, D_INNER);
    }
}

// Round 4
// 450.487 us; speedup vs baseline: 1.5418x; 1.5418x over previous
//
#include <hip/hip_runtime.h>
#include <hip/hip_bf16.h>
#include <math.h>

// Problem constants
#define D_MODEL 256
#define DEPTH 2
#define D_INNER 512
#define D_STATE 16
#define D_CONV 4
#define DT_RANK 16
#define BATCH 2
#define SEQLEN 2048
#define MROWS (BATCH * SEQLEN)   // 4096

typedef __attribute__((ext_vector_type(8))) short bf16x8;   // 8 bf16 in 4 VGPRs
typedef __attribute__((ext_vector_type(4))) float f32x4;

__device__ __forceinline__ float silu(float v) {
    return v / (1.0f + __expf(-v));
}

__device__ __forceinline__ ushort f2bf(float f) {
    union { float f; unsigned u; } v; v.f = f;
    unsigned r = v.u + 0x7FFFu + ((v.u >> 16) & 1u);
    return (ushort)(r >> 16);
}

// ---------------------------------------------------------------------------
// f32 -> bf16 elementwise (weights). n multiple of 1024.
// ---------------------------------------------------------------------------
__global__ __launch_bounds__(256) void cvt_bf16(
    const float* __restrict__ src, ushort* __restrict__ dst)
{
    int i = (blockIdx.x * 256 + threadIdx.x) * 4;
    float4 v = *(const float4*)(src + i);
    ushort4 o = { f2bf(v.x), f2bf(v.y), f2bf(v.z), f2bf(v.w) };
    *(ushort4*)(dst + i) = o;
}

// ---------------------------------------------------------------------------
// LayerNorm: one block per row of 256, bf16 output (feeds MFMA GEMM only).
// ---------------------------------------------------------------------------
__global__ __launch_bounds__(256) void ln_kernel(
    const float* __restrict__ x, const float* __restrict__ w,
    const float* __restrict__ b, ushort* __restrict__ h)
{
    int row = blockIdx.x;
    int t = threadIdx.x;
    float v = x[(size_t)row * D_MODEL + t];
    float s = v, sq = v * v;
    #pragma unroll
    for (int off = 32; off > 0; off >>= 1) {
        s  += __shfl_xor(s, off);
        sq += __shfl_xor(sq, off);
    }
    __shared__ float ss[4], ssq[4];
    int wv = t >> 6;
    if ((t & 63) == 0) { ss[wv] = s; ssq[wv] = sq; }
    __syncthreads();
    s  = ss[0] + ss[1] + ss[2] + ss[3];
    sq = ssq[0] + ssq[1] + ssq[2] + ssq[3];
    float mu  = s * (1.0f / D_MODEL);
    float var = sq * (1.0f / D_MODEL) - mu * mu;
    float r = rsqrtf(var + 1e-5f);
    h[(size_t)row * D_MODEL + t] = f2bf((v - mu) * r * w[t] + b[t]);
}

// ---------------------------------------------------------------------------
// bf16 MFMA NT GEMM: C = A(MxK,bf16) * B(NxK,bf16)^T, f32 accumulate.
// No LDS: fragments read straight from global (B panel is L2-resident).
// Block = 4 waves. WSPLITM=0: waves split N (block covers 16 m x 4*NF*16 n).
//                  WSPLITM=1: waves split M (block covers 64 m x NF*16 n).
// MODE 0: store transposed f32  CT[n][m]        (leading dim M)
// MODE 1: store row-major f32   C[m][n] + resid
// MODE 2: store row-major f32   C[m][n]
// ---------------------------------------------------------------------------
template<int NF, int MODE, int WSPLITM>
__global__ __launch_bounds__(256) void mma_nt(
    const ushort* __restrict__ A, const ushort* __restrict__ Bw,
    const float* __restrict__ resid, float* __restrict__ C,
    int M, int N, int K)
{
    int w    = threadIdx.x >> 6;
    int lane = threadIdx.x & 63;
    int l15  = lane & 15, quad = lane >> 4;
    int m0, nb;
    if (WSPLITM) { m0 = blockIdx.x * 64 + w * 16; nb = 0; }
    else         { m0 = blockIdx.x * 16;          nb = w * (NF * 16); }

    const ushort* Ap = A + (size_t)(m0 + l15) * K + quad * 8;
    f32x4 acc[NF];
    #pragma unroll
    for (int f = 0; f < NF; f++) acc[f] = (f32x4){0.f, 0.f, 0.f, 0.f};

    for (int k0 = 0; k0 < K; k0 += 32) {
        bf16x8 af = *(const bf16x8*)(Ap + k0);
        #pragma unroll
        for (int f = 0; f < NF; f++) {
            const ushort* Bp = Bw + (size_t)(nb + f * 16 + l15) * K + quad * 8 + k0;
            bf16x8 bf = *(const bf16x8*)Bp;
            acc[f] = __builtin_amdgcn_mfma_f32_16x16x32_bf16(af, bf, acc[f], 0, 0, 0);
        }
    }

    #pragma unroll
    for (int f = 0; f < NF; f++) {
        int n = nb + f * 16 + l15;
        if (MODE == 0) {
            *(float4*)(C + (size_t)n * M + m0 + quad * 4) = *(float4*)&acc[f];
        } else {
            #pragma unroll
            for (int r = 0; r < 4; r++) {
                int m = m0 + quad * 4 + r;
                float v = acc[f][r];
                if (MODE == 1) v += resid[(size_t)m * N + n];
                C[(size_t)m * N + n] = v;
            }
        }
    }
}

// ---------------------------------------------------------------------------
// Causal depthwise conv(4) + bias + SiLU on xi, and SiLU(z), all d-major.
// ---------------------------------------------------------------------------
__global__ __launch_bounds__(256) void convz_kernel(
    const float* __restrict__ xzT, const float* __restrict__ cw,
    const float* __restrict__ cb, float* __restrict__ xcT,
    float* __restrict__ zsT)
{
    int d = blockIdx.x;
    int row = blockIdx.y * 256 + threadIdx.x;
    int l = row & (SEQLEN - 1);
    const float* xi = xzT + (size_t)d * MROWS;
    float w0 = cw[d * D_CONV + 0], w1 = cw[d * D_CONV + 1];
    float w2 = cw[d * D_CONV + 2], w3 = cw[d * D_CONV + 3];
    float s = cb[d];
    if (l >= 3) s = fmaf(w0, xi[row - 3], s);
    if (l >= 2) s = fmaf(w1, xi[row - 2], s);
    if (l >= 1) s = fmaf(w2, xi[row - 1], s);
    s = fmaf(w3, xi[row], s);
    xcT[(size_t)d * MROWS + row] = silu(s);
    float z = xzT[(size_t)(D_INNER + d) * MROWS + row];
    zsT[(size_t)d * MROWS + row] = silu(z);
}

// ---------------------------------------------------------------------------
// Transpose + cvt: XT f32 [512][MROWS] (d-major) -> XB bf16 [MROWS][512].
// 64x64 LDS tile, padded stride 65 (<=2-way conflicts, free).
// ---------------------------------------------------------------------------
__global__ __launch_bounds__(256) void tconv_kernel(
    const float* __restrict__ XT, ushort* __restrict__ XB)
{
    __shared__ float tile[64][65];
    int tok0 = blockIdx.x * 64;
    int d0   = blockIdx.y * 64;
    int t  = threadIdx.x;
    int tx = t & 15, ty = t >> 4;
    #pragma unroll
    for (int i = 0; i < 4; i++) {
        float4 v = *(const float4*)(XT + (size_t)(d0 + ty + 16 * i) * MROWS + tok0 + tx * 4);
        *(float4*)&tile[ty + 16 * i][tx * 4] = v;
    }
    __syncthreads();
    #pragma unroll
    for (int i = 0; i < 4; i++) {
        int tok = tok0 + ty + 16 * i;
        ushort4 o;
        o.x = f2bf(tile[tx * 4 + 0][ty + 16 * i]);
        o.y = f2bf(tile[tx * 4 + 1][ty + 16 * i]);
        o.z = f2bf(tile[tx * 4 + 2][ty + 16 * i]);
        o.w = f2bf(tile[tx * 4 + 3][ty + 16 * i]);
        *(ushort4*)(XB + (size_t)tok * D_INNER + d0 + tx * 4) = o;
    }
}

// ---------------------------------------------------------------------------
// delta: delT[d][row] = softplus(dt[row]·dpw[d] + dpb[d]).
// Block = 256 rows x 16 d. dt in regs; dpw wave-uniform; coalesced stores.
// ---------------------------------------------------------------------------
__global__ __launch_bounds__(256) void delta_kernel(
    const float* __restrict__ dbl, const float* __restrict__ dpw,
    const float* __restrict__ dpb, float* __restrict__ delT)
{
    int row = blockIdx.x * 256 + threadIdx.x;
    int d0  = blockIdx.y * 16;
    float dts[DT_RANK];
    #pragma unroll
    for (int r = 0; r < DT_RANK; r++) dts[r] = dbl[(size_t)row * 48 + r];
    #pragma unroll
    for (int dd = 0; dd < 16; dd++) {
        int d = d0 + dd;
        const float* wr = dpw + (size_t)d * DT_RANK;
        float s = dpb[d];
        #pragma unroll
        for (int r = 0; r < DT_RANK; r++) s = fmaf(dts[r], wr[r], s);
        float sp = (s > 20.f) ? s : log1pf(__expf(s));
        delT[(size_t)d * MROWS + row] = sp;
    }
}

// ---------------------------------------------------------------------------
// bcT[e][row] = dbl[row][16+e].  Grid (row-tiles, 32 e).
// ---------------------------------------------------------------------------
__global__ __launch_bounds__(256) void bct_kernel(
    const float* __restrict__ dbl, float* __restrict__ bcT)
{
    int row = blockIdx.x * 256 + threadIdx.x;
    int e = blockIdx.y;
    bcT[(size_t)e * MROWS + row] = dbl[(size_t)row * 48 + DT_RANK + e];
}

// ---------------------------------------------------------------------------
// Selective scan, chunked parallel. Block = 512 thr = 32 chunks x 16 states
// per (b,d); LC=64.  8 waves/block, 4 blocks/CU -> full 32 waves/CU.
// ---------------------------------------------------------------------------
#define LC (SEQLEN / 32)   // 64 rows per chunk

__global__ __launch_bounds__(512) void scan_kernel(
    const float* __restrict__ delT, const float* __restrict__ xcT,
    const float* __restrict__ bcT, const float* __restrict__ zsT,
    const float* __restrict__ A_log, const float* __restrict__ Dp,
    float* __restrict__ yyT)
{
    int b = blockIdx.x >> 9;           // D_INNER == 512
    int d = blockIdx.x & 511;
    int t = threadIdx.x;
    int c = t >> 4, n = t & 15;        // chunk (0..31), state
    float a = -__expf(A_log[(size_t)d * D_STATE + n]);
    size_t base = (size_t)b * SEQLEN + (size_t)c * LC;

    const float* dlp = delT + (size_t)d * MROWS + base;
    const float* xvp = xcT  + (size_t)d * MROWS + base;
    const float* bnp = bcT  + (size_t)n * MROWS + base;
    const float* cnp = bcT  + (size_t)(D_STATE + n) * MROWS + base;
    const float* zsp = zsT  + (size_t)d * MROWS + base;
    float* yyp = yyT + (size_t)d * MROWS + base;

    __shared__ float Sarr[32][16];
    __shared__ float Parr[32][16];
    __shared__ float Hini[32][16];

    // Phase 1: chunk-local scan from h=0; accumulate sum(delta) for P.
    float h = 0.f, sd = 0.f;
    for (int j = 0; j < LC; j += 4) {
        float4 dl = *(const float4*)(dlp + j);
        float4 bn = *(const float4*)(bnp + j);
        float4 xv = *(const float4*)(xvp + j);
        sd += dl.x; h = fmaf(__expf(dl.x * a), h, dl.x * bn.x * xv.x);
        sd += dl.y; h = fmaf(__expf(dl.y * a), h, dl.y * bn.y * xv.y);
        sd += dl.z; h = fmaf(__expf(dl.z * a), h, dl.z * bn.z * xv.z);
        sd += dl.w; h = fmaf(__expf(dl.w * a), h, dl.w * bn.w * xv.w);
    }
    Sarr[c][n] = h;
    Parr[c][n] = __expf(a * sd);
    __syncthreads();

    // Phase 2: exclusive scan over the 32 chunk summaries (per state n).
    if (t < 16) {
        float hi = 0.f;
        #pragma unroll
        for (int cc = 0; cc < 32; cc++) {
            Hini[cc][t] = hi;
            hi = fmaf(Parr[cc][t], hi, Sarr[cc][t]);
        }
    }
    __syncthreads();

    // Phase 3: rescan from true initial state, produce gated output.
    h = Hini[c][n];
    float Dd = Dp[d];
    for (int j = 0; j < LC; j += 4) {
        float4 dl = *(const float4*)(dlp + j);
        float4 bn = *(const float4*)(bnp + j);
        float4 cn = *(const float4*)(cnp + j);
        float4 xv = *(const float4*)(xvp + j);
        float res[4];
        float dls[4] = {dl.x, dl.y, dl.z, dl.w};
        float bns[4] = {bn.x, bn.y, bn.z, bn.w};
        float cns[4] = {cn.x, cn.y, cn.z, cn.w};
        float xvs[4] = {xv.x, xv.y, xv.z, xv.w};
        #pragma unroll
        for (int jj = 0; jj < 4; jj++) {
            h = fmaf(__expf(dls[jj] * a), h, dls[jj] * bns[jj] * xvs[jj]);
            float p = h * cns[jj];
            p += __shfl_xor(p, 8, 16);
            p += __shfl_xor(p, 4, 16);
            p += __shfl_xor(p, 2, 16);
            p += __shfl_xor(p, 1, 16);
            res[jj] = p;
        }
        if (n == 0) {
            float4 zs = *(const float4*)(zsp + j);
            float4 o;
            o.x = (res[0] + xvs[0] * Dd) * zs.x;
            o.y = (res[1] + xvs[1] * Dd) * zs.y;
            o.z = (res[2] + xvs[2] * Dd) * zs.z;
            o.w = (res[3] + xvs[3] * Dd) * zs.w;
            *(float4*)(yyp + j) = o;
        }
    }
}

// ---------------------------------------------------------------------------
// Launch
// ---------------------------------------------------------------------------
extern "C" void kernel_launch(void* const* d_in, const int* in_sizes, int n_in,
                              void* d_out, int out_size, void* d_ws, size_t ws_size,
                              hipStream_t stream)
{
    const float* x    = (const float*)d_in[0];
    const float* lnw  = (const float*)d_in[1];
    const float* lnb  = (const float*)d_in[2];
    const float* ipw  = (const float*)d_in[3];
    const float* cw   = (const float*)d_in[4];
    const float* cb   = (const float*)d_in[5];
    const float* xpw  = (const float*)d_in[6];
    const float* dpw  = (const float*)d_in[7];
    const float* dpb  = (const float*)d_in[8];
    const float* alog = (const float*)d_in[9];
    const float* dpar = (const float*)d_in[10];
    const float* opw  = (const float*)d_in[11];
    float* out = (float*)d_out;

    // Workspace carve-up (bytes, 256-aligned)
    char* p = (char*)d_ws;
    auto alloc = [&](size_t bytes) { char* r = p; p += (bytes + 255) & ~(size_t)255; return r; };
    float*  xzT  = (float*)alloc((size_t)2 * D_INNER * MROWS * 4);  // 16 MB
    float*  xcT  = (float*)alloc((size_t)D_INNER * MROWS * 4);      // 8 MB
    float*  zsT  = (float*)alloc((size_t)D_INNER * MROWS * 4);      // 8 MB
    ushort* xcB  = (ushort*)alloc((size_t)MROWS * D_INNER * 2);     // 4 MB
    float*  dbl  = (float*)alloc((size_t)MROWS * 48 * 4);
    float*  bcT  = (float*)alloc((size_t)32 * MROWS * 4);
    ushort* yyB  = (ushort*)alloc((size_t)MROWS * D_INNER * 2);     // 4 MB
    ushort* hB   = (ushort*)alloc((size_t)MROWS * D_MODEL * 2);     // 2 MB
    float*  xbuf = (float*)alloc((size_t)MROWS * D_MODEL * 4);      // 4 MB
    ushort* ipwB = (ushort*)alloc((size_t)DEPTH * 2 * D_INNER * D_MODEL * 2);
    ushort* xpwB = (ushort*)alloc((size_t)DEPTH * 48 * D_INNER * 2);
    ushort* opwB = (ushort*)alloc((size_t)DEPTH * D_MODEL * D_INNER * 2);
    // delT / yyT alias xzT (dead after convz)
    float* delT = xzT;
    float* yyT  = xzT + (size_t)D_INNER * MROWS;

    // Weight conversions (f32 -> bf16), both layers at once
    cvt_bf16<<<DEPTH * 2 * D_INNER * D_MODEL / 1024, 256, 0, stream>>>(ipw, ipwB);
    cvt_bf16<<<DEPTH * 48 * D_INNER / 1024, 256, 0, stream>>>(xpw, xpwB);
    cvt_bf16<<<DEPTH * D_MODEL * D_INNER / 1024, 256, 0, stream>>>(opw, opwB);

    for (int lyr = 0; lyr < DEPTH; lyr++) {
        const float* xin = (lyr == 0) ? x : xbuf;
        float* xout = (lyr == DEPTH - 1) ? out : xbuf;

        ln_kernel<<<MROWS, 256, 0, stream>>>(
            xin, lnw + lyr * D_MODEL, lnb + lyr * D_MODEL, hB);

        // in_proj: [4096x256] x [1024x256]^T -> xzT (transposed, e-major)
        mma_nt<16, 0, 0><<<MROWS / 16, 256, 0, stream>>>(
            hB, ipwB + (size_t)lyr * 2 * D_INNER * D_MODEL, nullptr, xzT,
            MROWS, 2 * D_INNER, D_MODEL);

        convz_kernel<<<dim3(D_INNER, MROWS / 256), 256, 0, stream>>>(
            xzT, cw + (size_t)lyr * D_INNER * D_CONV, cb + lyr * D_INNER,
            xcT, zsT);

        tconv_kernel<<<dim3(MROWS / 64, D_INNER / 64), 256, 0, stream>>>(xcT, xcB);

        // x_proj: [4096x512] x [48x512]^T -> dbl row-major
        mma_nt<3, 2, 1><<<MROWS / 64, 256, 0, stream>>>(
            xcB, xpwB + (size_t)lyr * 48 * D_INNER, nullptr, dbl,
            MROWS, 48, D_INNER);

        delta_kernel<<<dim3(MROWS / 256, D_INNER / 16), 256, 0, stream>>>(
            dbl, dpw + (size_t)lyr * D_INNER * DT_RANK, dpb + lyr * D_INNER, delT);

        bct_kernel<<<dim3(MROWS / 256, 32), 256, 0, stream>>>(dbl, bcT);

        scan_kernel<<<BATCH * D_INNER, 512, 0, stream>>>(
            delT, xcT, bcT, zsT,
            alog + (size_t)lyr * D_INNER * D_STATE, dpar + lyr * D_INNER, yyT);

        tconv_kernel<<<dim3(MROWS / 64, D_INNER / 64), 256, 0, stream>>>(yyT, yyB);

        // out_proj: [4096x512] x [256x512]^T + resid -> xout row-major
        mma_nt<4, 1, 0><<<MROWS / 16, 256, 0, stream>>>(
            yyB, opwB + (size_t)lyr * D_MODEL * D_INNER, xin, xout,
            MROWS, D_MODEL, D_INNER);
    }
}

// Round 5
// 412.296 us; speedup vs baseline: 1.6846x; 1.0926x over previous
//
#include <hip/hip_runtime.h>
#include <hip/hip_bf16.h>
#include <math.h>

// Problem constants
#define D_MODEL 256
#define DEPTH 2
#define D_INNER 512
#define D_STATE 16
#define D_CONV 4
#define DT_RANK 16
#define BATCH 2
#define SEQLEN 2048
#define MROWS (BATCH * SEQLEN)   // 4096

typedef __attribute__((ext_vector_type(8))) short bf16x8;   // 8 bf16 in 4 VGPRs
typedef __attribute__((ext_vector_type(4))) float f32x4;

__device__ __forceinline__ float silu(float v) {
    return v / (1.0f + __expf(-v));
}

__device__ __forceinline__ ushort f2bf(float f) {
    union { float f; unsigned u; } v; v.f = f;
    unsigned r = v.u + 0x7FFFu + ((v.u >> 16) & 1u);
    return (ushort)(r >> 16);
}

// ---------------------------------------------------------------------------
// f32 -> bf16 elementwise (weights). n multiple of 1024.
// ---------------------------------------------------------------------------
__global__ __launch_bounds__(256) void cvt_bf16(
    const float* __restrict__ src, ushort* __restrict__ dst)
{
    int i = (blockIdx.x * 256 + threadIdx.x) * 4;
    float4 v = *(const float4*)(src + i);
    ushort4 o = { f2bf(v.x), f2bf(v.y), f2bf(v.z), f2bf(v.w) };
    *(ushort4*)(dst + i) = o;
}

// ---------------------------------------------------------------------------
// LayerNorm: one block per row of 256, bf16 output (feeds MFMA GEMM only).
// ---------------------------------------------------------------------------
__global__ __launch_bounds__(256) void ln_kernel(
    const float* __restrict__ x, const float* __restrict__ w,
    const float* __restrict__ b, ushort* __restrict__ h)
{
    int row = blockIdx.x;
    int t = threadIdx.x;
    float v = x[(size_t)row * D_MODEL + t];
    float s = v, sq = v * v;
    #pragma unroll
    for (int off = 32; off > 0; off >>= 1) {
        s  += __shfl_xor(s, off);
        sq += __shfl_xor(sq, off);
    }
    __shared__ float ss[4], ssq[4];
    int wv = t >> 6;
    if ((t & 63) == 0) { ss[wv] = s; ssq[wv] = sq; }
    __syncthreads();
    s  = ss[0] + ss[1] + ss[2] + ss[3];
    sq = ssq[0] + ssq[1] + ssq[2] + ssq[3];
    float mu  = s * (1.0f / D_MODEL);
    float var = sq * (1.0f / D_MODEL) - mu * mu;
    float r = rsqrtf(var + 1e-5f);
    h[(size_t)row * D_MODEL + t] = f2bf((v - mu) * r * w[t] + b[t]);
}

// ---------------------------------------------------------------------------
// bf16 MFMA NT GEMM: C = A(MxK,bf16) * B(NxK,bf16)^T, f32 accumulate.
// ---------------------------------------------------------------------------
template<int NF, int MODE, int WSPLITM>
__global__ __launch_bounds__(256) void mma_nt(
    const ushort* __restrict__ A, const ushort* __restrict__ Bw,
    const float* __restrict__ resid, float* __restrict__ C,
    int M, int N, int K)
{
    int w    = threadIdx.x >> 6;
    int lane = threadIdx.x & 63;
    int l15  = lane & 15, quad = lane >> 4;
    int m0, nb;
    if (WSPLITM) { m0 = blockIdx.x * 64 + w * 16; nb = 0; }
    else         { m0 = blockIdx.x * 16;          nb = w * (NF * 16); }

    const ushort* Ap = A + (size_t)(m0 + l15) * K + quad * 8;
    f32x4 acc[NF];
    #pragma unroll
    for (int f = 0; f < NF; f++) acc[f] = (f32x4){0.f, 0.f, 0.f, 0.f};

    for (int k0 = 0; k0 < K; k0 += 32) {
        bf16x8 af = *(const bf16x8*)(Ap + k0);
        #pragma unroll
        for (int f = 0; f < NF; f++) {
            const ushort* Bp = Bw + (size_t)(nb + f * 16 + l15) * K + quad * 8 + k0;
            bf16x8 bf = *(const bf16x8*)Bp;
            acc[f] = __builtin_amdgcn_mfma_f32_16x16x32_bf16(af, bf, acc[f], 0, 0, 0);
        }
    }

    #pragma unroll
    for (int f = 0; f < NF; f++) {
        int n = nb + f * 16 + l15;
        if (MODE == 0) {
            *(float4*)(C + (size_t)n * M + m0 + quad * 4) = *(float4*)&acc[f];
        } else {
            #pragma unroll
            for (int r = 0; r < 4; r++) {
                int m = m0 + quad * 4 + r;
                float v = acc[f][r];
                if (MODE == 1) v += resid[(size_t)m * N + n];
                C[(size_t)m * N + n] = v;
            }
        }
    }
}

// ---------------------------------------------------------------------------
// Causal depthwise conv(4) + bias + SiLU on xi, and SiLU(z), all d-major.
// ---------------------------------------------------------------------------
__global__ __launch_bounds__(256) void convz_kernel(
    const float* __restrict__ xzT, const float* __restrict__ cw,
    const float* __restrict__ cb, float* __restrict__ xcT,
    float* __restrict__ zsT)
{
    int d = blockIdx.x;
    int row = blockIdx.y * 256 + threadIdx.x;
    int l = row & (SEQLEN - 1);
    const float* xi = xzT + (size_t)d * MROWS;
    float w0 = cw[d * D_CONV + 0], w1 = cw[d * D_CONV + 1];
    float w2 = cw[d * D_CONV + 2], w3 = cw[d * D_CONV + 3];
    float s = cb[d];
    if (l >= 3) s = fmaf(w0, xi[row - 3], s);
    if (l >= 2) s = fmaf(w1, xi[row - 2], s);
    if (l >= 1) s = fmaf(w2, xi[row - 1], s);
    s = fmaf(w3, xi[row], s);
    xcT[(size_t)d * MROWS + row] = silu(s);
    float z = xzT[(size_t)(D_INNER + d) * MROWS + row];
    zsT[(size_t)d * MROWS + row] = silu(z);
}

// ---------------------------------------------------------------------------
// Transpose + cvt: XT f32 [512][MROWS] (d-major) -> XB bf16 [MROWS][512].
// ---------------------------------------------------------------------------
__global__ __launch_bounds__(256) void tconv_kernel(
    const float* __restrict__ XT, ushort* __restrict__ XB)
{
    __shared__ float tile[64][65];
    int tok0 = blockIdx.x * 64;
    int d0   = blockIdx.y * 64;
    int t  = threadIdx.x;
    int tx = t & 15, ty = t >> 4;
    #pragma unroll
    for (int i = 0; i < 4; i++) {
        float4 v = *(const float4*)(XT + (size_t)(d0 + ty + 16 * i) * MROWS + tok0 + tx * 4);
        *(float4*)&tile[ty + 16 * i][tx * 4] = v;
    }
    __syncthreads();
    #pragma unroll
    for (int i = 0; i < 4; i++) {
        int tok = tok0 + ty + 16 * i;
        ushort4 o;
        o.x = f2bf(tile[tx * 4 + 0][ty + 16 * i]);
        o.y = f2bf(tile[tx * 4 + 1][ty + 16 * i]);
        o.z = f2bf(tile[tx * 4 + 2][ty + 16 * i]);
        o.w = f2bf(tile[tx * 4 + 3][ty + 16 * i]);
        *(ushort4*)(XB + (size_t)tok * D_INNER + d0 + tx * 4) = o;
    }
}

// ---------------------------------------------------------------------------
// delta: delT[d][row] = softplus(dt[row]·dpw[d] + dpb[d]).
// ---------------------------------------------------------------------------
__global__ __launch_bounds__(256) void delta_kernel(
    const float* __restrict__ dbl, const float* __restrict__ dpw,
    const float* __restrict__ dpb, float* __restrict__ delT)
{
    int row = blockIdx.x * 256 + threadIdx.x;
    int d0  = blockIdx.y * 16;
    float dts[DT_RANK];
    #pragma unroll
    for (int r = 0; r < DT_RANK; r++) dts[r] = dbl[(size_t)row * 48 + r];
    #pragma unroll
    for (int dd = 0; dd < 16; dd++) {
        int d = d0 + dd;
        const float* wr = dpw + (size_t)d * DT_RANK;
        float s = dpb[d];
        #pragma unroll
        for (int r = 0; r < DT_RANK; r++) s = fmaf(dts[r], wr[r], s);
        float sp = (s > 20.f) ? s : log1pf(__expf(s));
        delT[(size_t)d * MROWS + row] = sp;
    }
}

// ---------------------------------------------------------------------------
// Selective scan v5 — shfl-free, all 16 states per thread.
// Block = 256 threads covers 2 d values: thread = (d2, b, c),
// d2 = t>>7, b = (t>>6)&1, c = t&63; chunk c = rows [c*32, c*32+32).
// Phase 1: chunk-local scan from h=0 (16 states in regs), summary to LDS.
// Phase 2: 64 scanner threads (d2,b,n) serially combine 64 chunks.
// Phase 3: rescan from true h_init; y = sum_n C_n h_n in-register;
//          fused D-skip + SiLU(z) gate; float4 stores.
// B/C are read straight from row-major dbl[row][16..48] (no bct pass).
// ---------------------------------------------------------------------------
#define LC 32
#define SSTR 20   // LDS summary stride (16 states + pad, 16B-aligned)

__global__ __launch_bounds__(256) void scan_kernel(
    const float* __restrict__ delT, const float* __restrict__ xcT,
    const float* __restrict__ dbl, const float* __restrict__ zsT,
    const float* __restrict__ A_log, const float* __restrict__ Dp,
    float* __restrict__ yyT)
{
    int t  = threadIdx.x;
    int d2 = t >> 7;
    int b  = (t >> 6) & 1;
    int c  = t & 63;
    int d  = blockIdx.x * 2 + d2;
    size_t base = (size_t)b * SEQLEN + (size_t)c * LC;   // row 0..4095

    float a[16];
    #pragma unroll
    for (int n = 0; n < 16; n++)
        a[n] = -__expf(A_log[(size_t)d * D_STATE + n]);

    const float* dlp = delT + (size_t)d * MROWS + base;
    const float* xvp = xcT  + (size_t)d * MROWS + base;
    const float* zsp = zsT  + (size_t)d * MROWS + base;
    float* yyp = yyT + (size_t)d * MROWS + base;

    __shared__ float Sarr[256 * SSTR];
    __shared__ float sdArr[256];

    // ---- Phase 1: chunk-local scan from h=0 ----
    float h[16];
    #pragma unroll
    for (int n = 0; n < 16; n++) h[n] = 0.f;
    float sd = 0.f;

    for (int j0 = 0; j0 < LC; j0 += 4) {
        float4 dl4 = *(const float4*)(dlp + j0);
        float4 xv4 = *(const float4*)(xvp + j0);
        float dls[4] = {dl4.x, dl4.y, dl4.z, dl4.w};
        float xvs[4] = {xv4.x, xv4.y, xv4.z, xv4.w};
        #pragma unroll
        for (int jj = 0; jj < 4; jj++) {
            float dl = dls[jj];
            float u  = dl * xvs[jj];
            const float* bp = dbl + (size_t)(base + j0 + jj) * 48 + 16;
            float Bv[16];
            *(float4*)&Bv[0]  = *(const float4*)(bp + 0);
            *(float4*)&Bv[4]  = *(const float4*)(bp + 4);
            *(float4*)&Bv[8]  = *(const float4*)(bp + 8);
            *(float4*)&Bv[12] = *(const float4*)(bp + 12);
            sd += dl;
            #pragma unroll
            for (int n = 0; n < 16; n++)
                h[n] = fmaf(__expf(dl * a[n]), h[n], Bv[n] * u);
        }
    }
    #pragma unroll
    for (int n = 0; n < 16; n++) Sarr[t * SSTR + n] = h[n];
    sdArr[t] = sd;
    __syncthreads();

    // ---- Phase 2: serial combine over 64 chunks per (d2,b), 16-way in n ----
    if (t < 64) {
        int sn  = t & 15;
        int sb  = (t >> 4) & 1;
        int sd2 = t >> 5;
        float as = -__expf(A_log[(size_t)(blockIdx.x * 2 + sd2) * D_STATE + sn]);
        float hi = 0.f;
        #pragma unroll 4
        for (int cc = 0; cc < 64; cc++) {
            int tid = (sd2 << 7) | (sb << 6) | cc;
            float sdc = sdArr[tid];
            float scn = Sarr[tid * SSTR + sn];
            Sarr[tid * SSTR + sn] = hi;           // exclusive prefix
            hi = fmaf(__expf(as * sdc), hi, scn);
        }
    }
    __syncthreads();

    // ---- Phase 3: rescan from true h_init, emit gated output ----
    #pragma unroll
    for (int n = 0; n < 16; n++) h[n] = Sarr[t * SSTR + n];
    float Dd = Dp[d];

    for (int j0 = 0; j0 < LC; j0 += 4) {
        float4 dl4 = *(const float4*)(dlp + j0);
        float4 xv4 = *(const float4*)(xvp + j0);
        float4 zs4 = *(const float4*)(zsp + j0);
        float dls[4] = {dl4.x, dl4.y, dl4.z, dl4.w};
        float xvs[4] = {xv4.x, xv4.y, xv4.z, xv4.w};
        float zss[4] = {zs4.x, zs4.y, zs4.z, zs4.w};
        float yv[4];
        #pragma unroll
        for (int jj = 0; jj < 4; jj++) {
            float dl = dls[jj];
            float u  = dl * xvs[jj];
            const float* bp = dbl + (size_t)(base + j0 + jj) * 48 + 16;
            float Bv[16], Cv[16];
            *(float4*)&Bv[0]  = *(const float4*)(bp + 0);
            *(float4*)&Bv[4]  = *(const float4*)(bp + 4);
            *(float4*)&Bv[8]  = *(const float4*)(bp + 8);
            *(float4*)&Bv[12] = *(const float4*)(bp + 12);
            *(float4*)&Cv[0]  = *(const float4*)(bp + 16);
            *(float4*)&Cv[4]  = *(const float4*)(bp + 20);
            *(float4*)&Cv[8]  = *(const float4*)(bp + 24);
            *(float4*)&Cv[12] = *(const float4*)(bp + 28);
            float y0 = 0.f, y1 = 0.f, y2 = 0.f, y3 = 0.f;
            #pragma unroll
            for (int n = 0; n < 16; n += 4) {
                h[n + 0] = fmaf(__expf(dl * a[n + 0]), h[n + 0], Bv[n + 0] * u);
                h[n + 1] = fmaf(__expf(dl * a[n + 1]), h[n + 1], Bv[n + 1] * u);
                h[n + 2] = fmaf(__expf(dl * a[n + 2]), h[n + 2], Bv[n + 2] * u);
                h[n + 3] = fmaf(__expf(dl * a[n + 3]), h[n + 3], Bv[n + 3] * u);
                y0 = fmaf(h[n + 0], Cv[n + 0], y0);
                y1 = fmaf(h[n + 1], Cv[n + 1], y1);
                y2 = fmaf(h[n + 2], Cv[n + 2], y2);
                y3 = fmaf(h[n + 3], Cv[n + 3], y3);
            }
            yv[jj] = ((y0 + y1) + (y2 + y3) + xvs[jj] * Dd) * zss[jj];
        }
        float4 o = { yv[0], yv[1], yv[2], yv[3] };
        *(float4*)(yyp + j0) = o;
    }
}

// ---------------------------------------------------------------------------
// Launch
// ---------------------------------------------------------------------------
extern "C" void kernel_launch(void* const* d_in, const int* in_sizes, int n_in,
                              void* d_out, int out_size, void* d_ws, size_t ws_size,
                              hipStream_t stream)
{
    const float* x    = (const float*)d_in[0];
    const float* lnw  = (const float*)d_in[1];
    const float* lnb  = (const float*)d_in[2];
    const float* ipw  = (const float*)d_in[3];
    const float* cw   = (const float*)d_in[4];
    const float* cb   = (const float*)d_in[5];
    const float* xpw  = (const float*)d_in[6];
    const float* dpw  = (const float*)d_in[7];
    const float* dpb  = (const float*)d_in[8];
    const float* alog = (const float*)d_in[9];
    const float* dpar = (const float*)d_in[10];
    const float* opw  = (const float*)d_in[11];
    float* out = (float*)d_out;

    // Workspace carve-up (bytes, 256-aligned)
    char* p = (char*)d_ws;
    auto alloc = [&](size_t bytes) { char* r = p; p += (bytes + 255) & ~(size_t)255; return r; };
    float*  xzT  = (float*)alloc((size_t)2 * D_INNER * MROWS * 4);  // 16 MB
    float*  xcT  = (float*)alloc((size_t)D_INNER * MROWS * 4);      // 8 MB
    float*  zsT  = (float*)alloc((size_t)D_INNER * MROWS * 4);      // 8 MB
    ushort* xcB  = (ushort*)alloc((size_t)MROWS * D_INNER * 2);     // 4 MB
    float*  dbl  = (float*)alloc((size_t)MROWS * 48 * 4);
    ushort* yyB  = (ushort*)alloc((size_t)MROWS * D_INNER * 2);     // 4 MB
    ushort* hB   = (ushort*)alloc((size_t)MROWS * D_MODEL * 2);     // 2 MB
    float*  xbuf = (float*)alloc((size_t)MROWS * D_MODEL * 4);      // 4 MB
    ushort* ipwB = (ushort*)alloc((size_t)DEPTH * 2 * D_INNER * D_MODEL * 2);
    ushort* xpwB = (ushort*)alloc((size_t)DEPTH * 48 * D_INNER * 2);
    ushort* opwB = (ushort*)alloc((size_t)DEPTH * D_MODEL * D_INNER * 2);
    // delT / yyT alias xzT (dead after convz)
    float* delT = xzT;
    float* yyT  = xzT + (size_t)D_INNER * MROWS;

    // Weight conversions (f32 -> bf16), both layers at once
    cvt_bf16<<<DEPTH * 2 * D_INNER * D_MODEL / 1024, 256, 0, stream>>>(ipw, ipwB);
    cvt_bf16<<<DEPTH * 48 * D_INNER / 1024, 256, 0, stream>>>(xpw, xpwB);
    cvt_bf16<<<DEPTH * D_MODEL * D_INNER / 1024, 256, 0, stream>>>(opw, opwB);

    for (int lyr = 0; lyr < DEPTH; lyr++) {
        const float* xin = (lyr == 0) ? x : xbuf;
        float* xout = (lyr == DEPTH - 1) ? out : xbuf;

        ln_kernel<<<MROWS, 256, 0, stream>>>(
            xin, lnw + lyr * D_MODEL, lnb + lyr * D_MODEL, hB);

        // in_proj: [4096x256] x [1024x256]^T -> xzT (transposed, e-major)
        mma_nt<16, 0, 0><<<MROWS / 16, 256, 0, stream>>>(
            hB, ipwB + (size_t)lyr * 2 * D_INNER * D_MODEL, nullptr, xzT,
            MROWS, 2 * D_INNER, D_MODEL);

        convz_kernel<<<dim3(D_INNER, MROWS / 256), 256, 0, stream>>>(
            xzT, cw + (size_t)lyr * D_INNER * D_CONV, cb + lyr * D_INNER,
            xcT, zsT);

        tconv_kernel<<<dim3(MROWS / 64, D_INNER / 64), 256, 0, stream>>>(xcT, xcB);

        // x_proj: [4096x512] x [48x512]^T -> dbl row-major
        mma_nt<3, 2, 1><<<MROWS / 64, 256, 0, stream>>>(
            xcB, xpwB + (size_t)lyr * 48 * D_INNER, nullptr, dbl,
            MROWS, 48, D_INNER);

        delta_kernel<<<dim3(MROWS / 256, D_INNER / 16), 256, 0, stream>>>(
            dbl, dpw + (size_t)lyr * D_INNER * DT_RANK, dpb + lyr * D_INNER, delT);

        scan_kernel<<<D_INNER / 2, 256, 0, stream>>>(
            delT, xcT, dbl, zsT,
            alog + (size_t)lyr * D_INNER * D_STATE, dpar + lyr * D_INNER, yyT);

        tconv_kernel<<<dim3(MROWS / 64, D_INNER / 64), 256, 0, stream>>>(yyT, yyB);

        // out_proj: [4096x512] x [256x512]^T + resid -> xout row-major
        mma_nt<4, 1, 0><<<MROWS / 16, 256, 0, stream>>>(
            yyB, opwB + (size_t)lyr * D_MODEL * D_INNER, xin, xout,
            MROWS, D_MODEL, D_INNER);
    }
}

// Round 6
// 349.024 us; speedup vs baseline: 1.9900x; 1.1813x over previous
//
#include <hip/hip_runtime.h>
#include <hip/hip_bf16.h>
#include <math.h>

// Problem constants
#define D_MODEL 256
#define DEPTH 2
#define D_INNER 512
#define D_STATE 16
#define D_CONV 4
#define DT_RANK 16
#define BATCH 2
#define SEQLEN 2048
#define MROWS (BATCH * SEQLEN)   // 4096

#define CCH 128   // chunks per batch-sequence
#define LCH 16    // rows per chunk (CCH*LCH == SEQLEN)

typedef __attribute__((ext_vector_type(8))) short bf16x8;   // 8 bf16 in 4 VGPRs
typedef __attribute__((ext_vector_type(4))) float f32x4;

__device__ __forceinline__ float silu(float v) {
    return v / (1.0f + __expf(-v));
}

__device__ __forceinline__ ushort f2bf(float f) {
    union { float f; unsigned u; } v; v.f = f;
    unsigned r = v.u + 0x7FFFu + ((v.u >> 16) & 1u);
    return (ushort)(r >> 16);
}

__device__ __forceinline__ float bf2f(ushort u) {
    union { unsigned u; float f; } v; v.u = ((unsigned)u) << 16;
    return v.f;
}

// ---------------------------------------------------------------------------
// f32 -> bf16 elementwise (weights). n multiple of 1024.
// ---------------------------------------------------------------------------
__global__ __launch_bounds__(256) void cvt_bf16(
    const float* __restrict__ src, ushort* __restrict__ dst)
{
    int i = (blockIdx.x * 256 + threadIdx.x) * 4;
    float4 v = *(const float4*)(src + i);
    ushort4 o = { f2bf(v.x), f2bf(v.y), f2bf(v.z), f2bf(v.w) };
    *(ushort4*)(dst + i) = o;
}

// ---------------------------------------------------------------------------
// LayerNorm: one block per row of 256, bf16 output (feeds MFMA GEMM only).
// ---------------------------------------------------------------------------
__global__ __launch_bounds__(256) void ln_kernel(
    const float* __restrict__ x, const float* __restrict__ w,
    const float* __restrict__ b, ushort* __restrict__ h)
{
    int row = blockIdx.x;
    int t = threadIdx.x;
    float v = x[(size_t)row * D_MODEL + t];
    float s = v, sq = v * v;
    #pragma unroll
    for (int off = 32; off > 0; off >>= 1) {
        s  += __shfl_xor(s, off);
        sq += __shfl_xor(sq, off);
    }
    __shared__ float ss[4], ssq[4];
    int wv = t >> 6;
    if ((t & 63) == 0) { ss[wv] = s; ssq[wv] = sq; }
    __syncthreads();
    s  = ss[0] + ss[1] + ss[2] + ss[3];
    sq = ssq[0] + ssq[1] + ssq[2] + ssq[3];
    float mu  = s * (1.0f / D_MODEL);
    float var = sq * (1.0f / D_MODEL) - mu * mu;
    float r = rsqrtf(var + 1e-5f);
    h[(size_t)row * D_MODEL + t] = f2bf((v - mu) * r * w[t] + b[t]);
}

// ---------------------------------------------------------------------------
// bf16 MFMA NT GEMM: C = A(MxK,bf16) * B(NxK,bf16)^T, f32 accumulate.
// MODE 1: row-major + resid; MODE 2: row-major.
// ---------------------------------------------------------------------------
template<int NF, int MODE, int WSPLITM>
__global__ __launch_bounds__(256) void mma_nt(
    const ushort* __restrict__ A, const ushort* __restrict__ Bw,
    const float* __restrict__ resid, float* __restrict__ C,
    int M, int N, int K)
{
    int w    = threadIdx.x >> 6;
    int lane = threadIdx.x & 63;
    int l15  = lane & 15, quad = lane >> 4;
    int m0, nb;
    if (WSPLITM) { m0 = blockIdx.x * 64 + w * 16; nb = 0; }
    else         { m0 = blockIdx.x * 16;          nb = w * (NF * 16); }

    const ushort* Ap = A + (size_t)(m0 + l15) * K + quad * 8;
    f32x4 acc[NF];
    #pragma unroll
    for (int f = 0; f < NF; f++) acc[f] = (f32x4){0.f, 0.f, 0.f, 0.f};

    for (int k0 = 0; k0 < K; k0 += 32) {
        bf16x8 af = *(const bf16x8*)(Ap + k0);
        #pragma unroll
        for (int f = 0; f < NF; f++) {
            const ushort* Bp = Bw + (size_t)(nb + f * 16 + l15) * K + quad * 8 + k0;
            bf16x8 bf = *(const bf16x8*)Bp;
            acc[f] = __builtin_amdgcn_mfma_f32_16x16x32_bf16(af, bf, acc[f], 0, 0, 0);
        }
    }

    #pragma unroll
    for (int f = 0; f < NF; f++) {
        int n = nb + f * 16 + l15;
        #pragma unroll
        for (int r = 0; r < 4; r++) {
            int m = m0 + quad * 4 + r;
            float v = acc[f][r];
            if (MODE == 1) v += resid[(size_t)m * N + n];
            C[(size_t)m * N + n] = v;
        }
    }
}

// ---------------------------------------------------------------------------
// Causal depthwise conv(4) + bias + SiLU, token-major, bf16 out.
// Thread = (row, d); lanes = consecutive d -> coalesced.
// ---------------------------------------------------------------------------
__global__ __launch_bounds__(256) void conv_tm(
    const float* __restrict__ xz, const float* __restrict__ cw,
    const float* __restrict__ cb, ushort* __restrict__ xcB)
{
    int lane = threadIdx.x & 63;
    int rr   = threadIdx.x >> 6;
    int row  = blockIdx.x * 4 + rr;
    int d    = blockIdx.y * 64 + lane;
    int l = row & (SEQLEN - 1);
    const float* xp = xz + (size_t)row * (2 * D_INNER) + d;
    float s = cb[d];
    if (l >= 3) s = fmaf(cw[d * 4 + 0], xp[-3 * 2 * D_INNER], s);
    if (l >= 2) s = fmaf(cw[d * 4 + 1], xp[-2 * 2 * D_INNER], s);
    if (l >= 1) s = fmaf(cw[d * 4 + 2], xp[-1 * 2 * D_INNER], s);
    s = fmaf(cw[d * 4 + 3], xp[0], s);
    xcB[(size_t)row * D_INNER + d] = f2bf(silu(s));
}

// ---------------------------------------------------------------------------
// delta token-major: delF[row][d] = softplus(dt[row]·dpw[d] + dpb[d]).
// ---------------------------------------------------------------------------
__global__ __launch_bounds__(256) void delta_tm(
    const float* __restrict__ dbl, const float* __restrict__ dpw,
    const float* __restrict__ dpb, float* __restrict__ delF)
{
    int lane = threadIdx.x & 63;
    int rr   = threadIdx.x >> 6;
    int row  = blockIdx.x * 4 + rr;
    int d    = blockIdx.y * 64 + lane;
    const float* dt = dbl + (size_t)row * 48;
    const float* wr = dpw + (size_t)d * DT_RANK;
    float s = dpb[d];
    #pragma unroll
    for (int r = 0; r < DT_RANK; r++) s = fmaf(dt[r], wr[r], s);
    float sp = (s > 20.f) ? s : log1pf(__expf(s));
    delF[(size_t)row * D_INNER + d] = sp;
}

// ---------------------------------------------------------------------------
// Scan K1: per-(b,d,chunk) partial scan from h=0 -> summaries.
// Block 256 = 64 d-lanes x 4 chunks. Grid 512: [dt:3][b:1][ct:5].
// Ssum layout: [b][c][n][d] (coalesced over d). sdsum: [b][c][d].
// ---------------------------------------------------------------------------
__global__ __launch_bounds__(256) void scan_sum(
    const float* __restrict__ delF, const ushort* __restrict__ xcB,
    const float* __restrict__ dbl, const float* __restrict__ A_log,
    float* __restrict__ Ssum, float* __restrict__ sdsum)
{
    int bid = blockIdx.x;
    int ct = bid & 31;
    int b  = (bid >> 5) & 1;
    int dt = bid >> 6;
    int lane = threadIdx.x & 63;
    int cw_  = threadIdx.x >> 6;
    int d = dt * 64 + lane;
    int c = ct * 4 + cw_;
    int row0 = b * SEQLEN + c * LCH;

    float a[16];
    #pragma unroll
    for (int n = 0; n < 16; n++)
        a[n] = -__expf(A_log[(size_t)d * D_STATE + n]);

    float h[16];
    #pragma unroll
    for (int n = 0; n < 16; n++) h[n] = 0.f;
    float sd = 0.f;

    #pragma unroll 2
    for (int j = 0; j < LCH; j++) {
        int row = row0 + j;
        float dl = delF[(size_t)row * D_INNER + d];
        float xv = bf2f(xcB[(size_t)row * D_INNER + d]);
        float u  = dl * xv;
        sd += dl;
        const float* bp = dbl + (size_t)row * 48 + 16;
        float Bv[16];
        *(float4*)&Bv[0]  = *(const float4*)(bp + 0);
        *(float4*)&Bv[4]  = *(const float4*)(bp + 4);
        *(float4*)&Bv[8]  = *(const float4*)(bp + 8);
        *(float4*)&Bv[12] = *(const float4*)(bp + 12);
        #pragma unroll
        for (int n = 0; n < 16; n++)
            h[n] = fmaf(__expf(dl * a[n]), h[n], Bv[n] * u);
    }
    size_t sbase = ((size_t)(b * CCH + c) * 16) * D_INNER + d;
    #pragma unroll
    for (int n = 0; n < 16; n++) Ssum[sbase + (size_t)n * D_INNER] = h[n];
    sdsum[(size_t)(b * CCH + c) * D_INNER + d] = sd;
}

// ---------------------------------------------------------------------------
// Scan K2: in-place exclusive prefix over chunk summaries.
// Thread = (b,n,d); 64 blocks x 256. Serial over CCH chunks.
// ---------------------------------------------------------------------------
__global__ __launch_bounds__(256) void scan_comb(
    const float* __restrict__ A_log, const float* __restrict__ sdsum,
    float* __restrict__ Ssum)
{
    int bid = blockIdx.x;           // [b:1][n:4][dt:1]
    int dt = bid & 1;
    int n  = (bid >> 1) & 15;
    int b  = bid >> 5;
    int d  = dt * 256 + threadIdx.x;
    float a = -__expf(A_log[(size_t)d * D_STATE + n]);
    float hi = 0.f;
    #pragma unroll 4
    for (int c = 0; c < CCH; c++) {
        size_t idx = ((size_t)(b * CCH + c) * 16 + n) * D_INNER + d;
        float s  = Ssum[idx];
        float sd = sdsum[(size_t)(b * CCH + c) * D_INNER + d];
        Ssum[idx] = hi;
        hi = fmaf(__expf(a * sd), hi, s);
    }
}

// ---------------------------------------------------------------------------
// Scan K3: rescan from true h_init; y = sum_n C_n h_n + D-skip, SiLU(z) gate;
// emits yy as bf16 token-major (feeds out_proj MFMA directly).
// ---------------------------------------------------------------------------
__global__ __launch_bounds__(256) void scan_emit(
    const float* __restrict__ delF, const ushort* __restrict__ xcB,
    const float* __restrict__ xz, const float* __restrict__ dbl,
    const float* __restrict__ Hini, const float* __restrict__ A_log,
    const float* __restrict__ Dp, ushort* __restrict__ yyB)
{
    int bid = blockIdx.x;
    int ct = bid & 31;
    int b  = (bid >> 5) & 1;
    int dt = bid >> 6;
    int lane = threadIdx.x & 63;
    int cw_  = threadIdx.x >> 6;
    int d = dt * 64 + lane;
    int c = ct * 4 + cw_;
    int row0 = b * SEQLEN + c * LCH;

    float a[16];
    #pragma unroll
    for (int n = 0; n < 16; n++)
        a[n] = -__expf(A_log[(size_t)d * D_STATE + n]);

    float h[16];
    size_t sbase = ((size_t)(b * CCH + c) * 16) * D_INNER + d;
    #pragma unroll
    for (int n = 0; n < 16; n++) h[n] = Hini[sbase + (size_t)n * D_INNER];
    float Dd = Dp[d];

    #pragma unroll 2
    for (int j = 0; j < LCH; j++) {
        int row = row0 + j;
        float dl = delF[(size_t)row * D_INNER + d];
        float xv = bf2f(xcB[(size_t)row * D_INNER + d]);
        float z  = xz[(size_t)row * (2 * D_INNER) + D_INNER + d];
        float u  = dl * xv;
        const float* bp = dbl + (size_t)row * 48 + 16;
        float Bv[16], Cv[16];
        *(float4*)&Bv[0]  = *(const float4*)(bp + 0);
        *(float4*)&Bv[4]  = *(const float4*)(bp + 4);
        *(float4*)&Bv[8]  = *(const float4*)(bp + 8);
        *(float4*)&Bv[12] = *(const float4*)(bp + 12);
        *(float4*)&Cv[0]  = *(const float4*)(bp + 16);
        *(float4*)&Cv[4]  = *(const float4*)(bp + 20);
        *(float4*)&Cv[8]  = *(const float4*)(bp + 24);
        *(float4*)&Cv[12] = *(const float4*)(bp + 28);
        float y0 = 0.f, y1 = 0.f, y2 = 0.f, y3 = 0.f;
        #pragma unroll
        for (int n = 0; n < 16; n += 4) {
            h[n + 0] = fmaf(__expf(dl * a[n + 0]), h[n + 0], Bv[n + 0] * u);
            h[n + 1] = fmaf(__expf(dl * a[n + 1]), h[n + 1], Bv[n + 1] * u);
            h[n + 2] = fmaf(__expf(dl * a[n + 2]), h[n + 2], Bv[n + 2] * u);
            h[n + 3] = fmaf(__expf(dl * a[n + 3]), h[n + 3], Bv[n + 3] * u);
            y0 = fmaf(h[n + 0], Cv[n + 0], y0);
            y1 = fmaf(h[n + 1], Cv[n + 1], y1);
            y2 = fmaf(h[n + 2], Cv[n + 2], y2);
            y3 = fmaf(h[n + 3], Cv[n + 3], y3);
        }
        float y = (y0 + y1) + (y2 + y3) + xv * Dd;
        yyB[(size_t)row * D_INNER + d] = f2bf(y * silu(z));
    }
}

// ---------------------------------------------------------------------------
// Launch
// ---------------------------------------------------------------------------
extern "C" void kernel_launch(void* const* d_in, const int* in_sizes, int n_in,
                              void* d_out, int out_size, void* d_ws, size_t ws_size,
                              hipStream_t stream)
{
    const float* x    = (const float*)d_in[0];
    const float* lnw  = (const float*)d_in[1];
    const float* lnb  = (const float*)d_in[2];
    const float* ipw  = (const float*)d_in[3];
    const float* cw   = (const float*)d_in[4];
    const float* cb   = (const float*)d_in[5];
    const float* xpw  = (const float*)d_in[6];
    const float* dpw  = (const float*)d_in[7];
    const float* dpb  = (const float*)d_in[8];
    const float* alog = (const float*)d_in[9];
    const float* dpar = (const float*)d_in[10];
    const float* opw  = (const float*)d_in[11];
    float* out = (float*)d_out;

    // Workspace carve-up (bytes, 256-aligned)
    char* p = (char*)d_ws;
    auto alloc = [&](size_t bytes) { char* r = p; p += (bytes + 255) & ~(size_t)255; return r; };
    float*  xz   = (float*)alloc((size_t)MROWS * 2 * D_INNER * 4);  // 16 MB
    ushort* xcB  = (ushort*)alloc((size_t)MROWS * D_INNER * 2);     // 4 MB
    float*  dbl  = (float*)alloc((size_t)MROWS * 48 * 4);           // 0.75 MB
    float*  delF = (float*)alloc((size_t)MROWS * D_INNER * 4);      // 8 MB
    float*  Ssum = (float*)alloc((size_t)BATCH * CCH * 16 * D_INNER * 4);  // 8 MB
    float*  sdsum= (float*)alloc((size_t)BATCH * CCH * D_INNER * 4);       // 0.5 MB
    ushort* yyB  = (ushort*)alloc((size_t)MROWS * D_INNER * 2);     // 4 MB
    ushort* hB   = (ushort*)alloc((size_t)MROWS * D_MODEL * 2);     // 2 MB
    float*  xbuf = (float*)alloc((size_t)MROWS * D_MODEL * 4);      // 4 MB
    ushort* ipwB = (ushort*)alloc((size_t)DEPTH * 2 * D_INNER * D_MODEL * 2);
    ushort* xpwB = (ushort*)alloc((size_t)DEPTH * 48 * D_INNER * 2);
    ushort* opwB = (ushort*)alloc((size_t)DEPTH * D_MODEL * D_INNER * 2);

    // Weight conversions (f32 -> bf16), both layers at once
    cvt_bf16<<<DEPTH * 2 * D_INNER * D_MODEL / 1024, 256, 0, stream>>>(ipw, ipwB);
    cvt_bf16<<<DEPTH * 48 * D_INNER / 1024, 256, 0, stream>>>(xpw, xpwB);
    cvt_bf16<<<DEPTH * D_MODEL * D_INNER / 1024, 256, 0, stream>>>(opw, opwB);

    for (int lyr = 0; lyr < DEPTH; lyr++) {
        const float* xin = (lyr == 0) ? x : xbuf;
        float* xout = (lyr == DEPTH - 1) ? out : xbuf;
        const float* alogL = alog + (size_t)lyr * D_INNER * D_STATE;

        ln_kernel<<<MROWS, 256, 0, stream>>>(
            xin, lnw + lyr * D_MODEL, lnb + lyr * D_MODEL, hB);

        // in_proj: [4096x256] x [1024x256]^T -> xz row-major f32
        mma_nt<16, 2, 0><<<MROWS / 16, 256, 0, stream>>>(
            hB, ipwB + (size_t)lyr * 2 * D_INNER * D_MODEL, nullptr, xz,
            MROWS, 2 * D_INNER, D_MODEL);

        conv_tm<<<dim3(MROWS / 4, D_INNER / 64), 256, 0, stream>>>(
            xz, cw + (size_t)lyr * D_INNER * D_CONV, cb + lyr * D_INNER, xcB);

        // x_proj: [4096x512] x [48x512]^T -> dbl row-major
        mma_nt<3, 2, 1><<<MROWS / 64, 256, 0, stream>>>(
            xcB, xpwB + (size_t)lyr * 48 * D_INNER, nullptr, dbl,
            MROWS, 48, D_INNER);

        delta_tm<<<dim3(MROWS / 4, D_INNER / 64), 256, 0, stream>>>(
            dbl, dpw + (size_t)lyr * D_INNER * DT_RANK, dpb + lyr * D_INNER, delF);

        scan_sum<<<512, 256, 0, stream>>>(delF, xcB, dbl, alogL, Ssum, sdsum);
        scan_comb<<<64, 256, 0, stream>>>(alogL, sdsum, Ssum);
        scan_emit<<<512, 256, 0, stream>>>(delF, xcB, xz, dbl, Ssum, alogL,
                                           dpar + lyr * D_INNER, yyB);

        // out_proj: [4096x512] x [256x512]^T + resid -> xout row-major
        mma_nt<4, 1, 0><<<MROWS / 16, 256, 0, stream>>>(
            yyB, opwB + (size_t)lyr * D_MODEL * D_INNER, xin, xout,
            MROWS, D_MODEL, D_INNER);
    }
}